// Round 4
// baseline (218.512 us; speedup 1.0000x reference)
//
#include <hip/hip_runtime.h>
#include <hip/hip_bf16.h>

// OTNoiseGate: B=8192, E=8, D=512, P=32, eps=0.05, 50 Sinkhorn iters.
// R4: BPB=64 (1024 blocks, 3 blocks/CU), register-prefetch K-pipeline,
// [k-octet][row] bf16x8 LDS layout (bank-minimal b128 traffic), proto norms
// folded in-kernel, Sinkhorn at 4 lanes/problem (all waves active in tail).

#define EXP2F(x) __builtin_amdgcn_exp2f(x)
#define LOG2F(x) __builtin_amdgcn_logf(x)   // v_log_f32 = log2
#define RCPF(x)  __builtin_amdgcn_rcpf(x)

typedef __bf16 bf16x8 __attribute__((ext_vector_type(8)));
typedef float  f32x4  __attribute__((ext_vector_type(4)));

#define BDIM 8192
#define EDIM 8
#define DDIM 512
#define PDIM 32
#define BPB  64             // b's (problems) per block
#define MROWS 128           // 64 token rows + 64 anchor rows
#define NTHR 256
#define CSTRIDE 36          // floats per cost row (32 + 4 pad), 16B-aligned
#define C_SCALE 28.853900817779268f   // log2(e)/eps
#define LOG2E   1.4426950408889634f

__device__ __forceinline__ bf16x8 cvt2(float4 a, float4 b) {
  bf16x8 r;
  r[0] = (__bf16)a.x; r[1] = (__bf16)a.y; r[2] = (__bf16)a.z; r[3] = (__bf16)a.w;
  r[4] = (__bf16)b.x; r[5] = (__bf16)b.y; r[6] = (__bf16)b.z; r[7] = (__bf16)b.w;
  return r;
}

__global__ __launch_bounds__(NTHR, 3)
void ot_noise_gate_kernel(const float* __restrict__ tokens,
                          const float* __restrict__ protos,
                          const int*   __restrict__ fullIndexPtr,
                          float*       __restrict__ out) {
  const int fi    = fullIndexPtr[0];
  const int e     = blockIdx.x & (EDIM - 1);       // chunk-major for anchor reuse
  const int chunk = blockIdx.x >> 3;
  const int b0    = chunk * BPB;
  float* outVal = out;                             // validity (B,E,1)
  float* outOt  = out + BDIM * EDIM;               // ot_cost  (B,E)

  if (e == fi) {
    int t = threadIdx.x;
    if (t < BPB) {
      int b = b0 + t;
      outVal[b * EDIM + e] = 1.0f;
      outOt [b * EDIM + e] = 0.0f;
    }
    return;
  }

  // LDS: sB [64 k-octets][32 p] bf16x8 = 32 KiB (full K, bank-minimal)
  //      sA [8 k-octets][128 rows] bf16x8 = 16 KiB, overlaid by sC (18 KiB)
  __shared__ __align__(16) __bf16 sB[64 * PDIM * 8];
  __shared__ __align__(16) unsigned char sACraw[MROWS * CSTRIDE * 4];
  __shared__ float sNorm[MROWS];
  __shared__ float sPNp[8][33];
  __shared__ float sPN[PDIM];
  __bf16* sA = (__bf16*)sACraw;
  float*  sC = (float*)sACraw;

  const int t   = threadIdx.x;
  const int l   = t & 63;
  const int w   = t >> 6;             // wave 0..3
  const int fr  = l & 15;             // fragment lane index
  const int q4  = l >> 4;             // k-quarter selector

  // ---- A prefetch setup: 2 threads per row, 8 float4 (128B) each -----------
  const int row = t >> 1;             // 0..127 (0..63 tokens, 64..127 anchors)
  const int h   = t & 1;              // K-half of the 64-float chunk
  const float4* rowPtr = (const float4*)(tokens +
      ((size_t)(b0 + (row & 63)) * EDIM + ((row < 64) ? e : fi)) * DDIM);

  float4 pf[8];
  #pragma unroll
  for (int i2 = 0; i2 < 8; ++i2) pf[i2] = rowPtr[h * 8 + i2];   // chunk 0

  // ---- stage protos[e] -> sB (bf16) + fp32 norm partials --------------------
  {
    const float4* pG4 = (const float4*)(protos + (size_t)e * PDIM * DDIM);
    const int p  = t & 31;
    const int oh = t >> 5;            // 0..7
    float pnp = 0.f;
    #pragma unroll
    for (int pass = 0; pass < 8; ++pass) {
      int oct = oh * 8 + pass;
      float4 a = pG4[p * 128 + oct * 2];
      float4 b = pG4[p * 128 + oct * 2 + 1];
      pnp += a.x*a.x + a.y*a.y + a.z*a.z + a.w*a.w
           + b.x*b.x + b.y*b.y + b.z*b.z + b.w*b.w;
      *(bf16x8*)&sB[(oct * PDIM + p) * 8] = cvt2(a, b);
    }
    sPNp[oh][p] = pnp;
  }
  __syncthreads();                                   // B-tile + pn partials
  if (t < PDIM) {
    float s = 0.f;
    #pragma unroll
    for (int o = 0; o < 8; ++o) s += sPNp[o][t];
    sPN[t] = s;                                      // visible via later barriers
  }

  // ---- K-chunk pipeline -----------------------------------------------------
  f32x4 acc[2][2];
  #pragma unroll
  for (int mt = 0; mt < 2; ++mt)
    #pragma unroll
    for (int nt = 0; nt < 2; ++nt)
      acc[mt][nt] = (f32x4){0.f, 0.f, 0.f, 0.f};
  float ss = 0.f;

  for (int kc = 0; kc < 8; ++kc) {
    // write phase: consume pf (cvt + norm partial + bank-minimal b128 writes)
    #pragma unroll
    for (int ii = 0; ii < 4; ++ii) {
      float4 a = pf[2 * ii], b = pf[2 * ii + 1];
      ss += a.x*a.x + a.y*a.y + a.z*a.z + a.w*a.w
          + b.x*b.x + b.y*b.y + b.z*b.z + b.w*b.w;
      *(bf16x8*)&sA[((h * 4 + ii) * MROWS + row) * 8] = cvt2(a, b);
    }
    __syncthreads();

    if (kc < 7) {                    // prefetch next chunk; lands during MFMA
      #pragma unroll
      for (int i2 = 0; i2 < 8; ++i2)
        pf[i2] = rowPtr[(kc + 1) * 16 + h * 8 + i2];
    }

    // MFMA phase
    #pragma unroll
    for (int ks = 0; ks < 2; ++ks) {
      bf16x8 bf0 = *(const bf16x8*)&sB[((kc * 8 + ks * 4 + q4) * PDIM + fr) * 8];
      bf16x8 bf1 = *(const bf16x8*)&sB[((kc * 8 + ks * 4 + q4) * PDIM + 16 + fr) * 8];
      #pragma unroll
      for (int mt = 0; mt < 2; ++mt) {
        bf16x8 af = *(const bf16x8*)&sA[((ks * 4 + q4) * MROWS + w * 32 + mt * 16 + fr) * 8];
        acc[mt][0] = __builtin_amdgcn_mfma_f32_16x16x32_bf16(af, bf0, acc[mt][0], 0, 0, 0);
        acc[mt][1] = __builtin_amdgcn_mfma_f32_16x16x32_bf16(af, bf1, acc[mt][1], 0, 0, 0);
      }
    }
    __syncthreads();
  }

  // ---- row norms: partner lanes hold the two K-halves of one row ------------
  ss += __shfl_xor(ss, 1);
  if (h == 0) sNorm[row] = ss;
  __syncthreads();

  // ---- epilogue: cost = max(||x||^2 - 2*cross + ||p||^2, 0) -> sC (overlay) -
  {
    float pp0 = sPN[fr], pp1 = sPN[16 + fr];
    #pragma unroll
    for (int mt = 0; mt < 2; ++mt)
      #pragma unroll
      for (int reg = 0; reg < 4; ++reg) {
        int r2 = w * 32 + mt * 16 + q4 * 4 + reg;    // C/D: row=(l>>4)*4+reg
        float nrm = sNorm[r2];
        sC[r2 * CSTRIDE + fr]      = fmaxf(nrm - 2.f * acc[mt][0][reg] + pp0, 0.f);
        sC[r2 * CSTRIDE + 16 + fr] = fmaxf(nrm - 2.f * acc[mt][1][reg] + pp1, 0.f);
      }
  }
  __syncthreads();

  // ---- Sinkhorn: 4 lanes per problem, 8 p each (all waves active) -----------
  const int i  = t >> 2;              // problem 0..63
  const int q2 = t & 3;               // p in [8*q2, 8*q2+8)
  float c0[8], c1[8];
  {
    const float4* r0 = (const float4*)&sC[i * CSTRIDE + q2 * 8];
    const float4* r1 = (const float4*)&sC[(64 + i) * CSTRIDE + q2 * 8];
    #pragma unroll
    for (int r = 0; r < 2; ++r) {
      float4 a = r0[r];
      float4 b = r1[r];
      c0[4*r] = a.x; c0[4*r+1] = a.y; c0[4*r+2] = a.z; c0[4*r+3] = a.w;
      c1[4*r] = b.x; c1[4*r+1] = b.y; c1[4*r+2] = b.z; c1[4*r+3] = b.w;
    }
  }

  float W[8], dc[8];
  float sum0 = 0.f, mA = -1e30f, mB = -1e30f;
  #pragma unroll
  for (int r = 0; r < 8; ++r) {
    float ka = -c0[r] * C_SCALE, kb = -c1[r] * C_SCALE;
    dc[r] = c1[r] - c0[r];
    sum0 += c0[r];
    mA = fmaxf(mA, ka);
    mB = fmaxf(mB, kb);
  }
  mA = fmaxf(mA, __shfl_xor(mA, 1)); mA = fmaxf(mA, __shfl_xor(mA, 2));
  mB = fmaxf(mB, __shfl_xor(mB, 1)); mB = fmaxf(mB, __shfl_xor(mB, 2));
  float sa = 0.f, sb = 0.f;
  #pragma unroll
  for (int r = 0; r < 8; ++r) {
    float ka = -c0[r] * C_SCALE, kb = -c1[r] * C_SCALE;
    sa += EXP2F(ka - mA);
    sb += EXP2F(kb - mB);
    W[r] = EXP2F(C_SCALE * dc[r]);    // 2^(k0-k1)
  }
  sa += __shfl_xor(sa, 1); sa += __shfl_xor(sa, 2);
  sb += __shfl_xor(sb, 1); sb += __shfl_xor(sb, 2);
  sum0 += __shfl_xor(sum0, 1); sum0 += __shfl_xor(sum0, 2);
  // iteration 1 (reference: lv=0): delta1 = lse2(k1) - lse2(k0)
  float delta = (mB + LOG2F(sb)) - (mA + LOG2F(sa));

  // iterations 2..50
  for (int it = 0; it < 49; ++it) {
    float s = EXP2F(delta);
    float T = 0.f;
    #pragma unroll
    for (int r = 0; r < 8; ++r)
      T += RCPF(__builtin_fmaf(W[r], s, 1.0f));   // sigma_p
    T += __shfl_xor(T, 1);
    T += __shfl_xor(T, 2);            // in (0,32)
    delta += LOG2F(T) - LOG2F(32.0f - T);
  }

  // ---- final transport & outputs -------------------------------------------
  float s = EXP2F(delta), sv = 0.f;
  #pragma unroll
  for (int r = 0; r < 8; ++r)
    sv += RCPF(__builtin_fmaf(W[r], s, 1.0f)) * dc[r];
  sv += __shfl_xor(sv, 1);
  sv += __shfl_xor(sv, 2);
  if (q2 == 0) {
    int b = b0 + i;
    float ot  = (sum0 + sv) * 0.03125f;
    float val = RCPF(1.0f + EXP2F(LOG2E * 6.0f * (ot - 0.25f)));
    outVal[b * EDIM + e] = val;
    outOt [b * EDIM + e] = ot;
  }
}

extern "C" void kernel_launch(void* const* d_in, const int* in_sizes, int n_in,
                              void* d_out, int out_size, void* d_ws, size_t ws_size,
                              hipStream_t stream) {
  const float* tokens = (const float*)d_in[0];   // (8192, 8, 512) fp32
  const float* protos = (const float*)d_in[1];   // (8, 32, 512) fp32
  const int*   fidx   = (const int*)d_in[2];     // scalar
  float* out = (float*)d_out;                    // 65536 validity + 65536 ot

  dim3 grid((BDIM / BPB) * EDIM);                // 1024 blocks, chunk-major
  ot_noise_gate_kernel<<<grid, NTHR, 0, stream>>>(tokens, protos, fidx, out);
}

// Round 5
// 208.300 us; speedup vs baseline: 1.0490x; 1.0490x over previous
//
#include <hip/hip_runtime.h>
#include <hip/hip_bf16.h>

// OTNoiseGate: B=8192, E=8, D=512, P=32, eps=0.05, 50 Sinkhorn iters.
// R5: barrier-free structure. Each wave owns 8 problems: M-tile = [8 token
// rows; 8 anchor rows] x 32 protos, A-fragments loaded DIRECTLY from global
// in MFMA layout (no A LDS, no per-chunk barriers). B (protos, bf16) staged
// once to LDS -> single __syncthreads in the kernel. Cost->Sinkhorn handoff
// through a wave-private LDS tile (DS pipe is in-order per wave). Sinkhorn:
// ns=2 scalar recurrence, 8 lanes/problem, ballot early-exit at fp32 noise.

#define EXP2F(x) __builtin_amdgcn_exp2f(x)
#define LOG2F(x) __builtin_amdgcn_logf(x)   // v_log_f32 = log2
#define RCPF(x)  __builtin_amdgcn_rcpf(x)

typedef __bf16 bf16x8 __attribute__((ext_vector_type(8)));
typedef float  f32x4  __attribute__((ext_vector_type(4)));

#define BDIM 8192
#define EDIM 8
#define DDIM 512
#define PDIM 32
#define BPB  32             // problems per block (8 per wave x 4 waves)
#define NTHR 256
#define C_SCALE 28.853900817779268f   // log2(e)/eps
#define LOG2E   1.4426950408889634f

__device__ __forceinline__ bf16x8 cvt2(float4 a, float4 b) {
  bf16x8 r;
  r[0] = (__bf16)a.x; r[1] = (__bf16)a.y; r[2] = (__bf16)a.z; r[3] = (__bf16)a.w;
  r[4] = (__bf16)b.x; r[5] = (__bf16)b.y; r[6] = (__bf16)b.z; r[7] = (__bf16)b.w;
  return r;
}

__global__ __launch_bounds__(NTHR, 3)    // 3 blocks/CU (LDS-capped), VGPR<=170
void ot_noise_gate_kernel(const float* __restrict__ tokens,
                          const float* __restrict__ protos,
                          const int*   __restrict__ fullIndexPtr,
                          float*       __restrict__ out) {
  const int fi    = fullIndexPtr[0];
  const int e     = blockIdx.x & (EDIM - 1);   // chunk-major: anchor L3 reuse
  const int b0    = (blockIdx.x >> 3) * BPB;
  float* outVal = out;                         // validity (B,E,1)
  float* outOt  = out + BDIM * EDIM;           // ot_cost  (B,E)

  if (e == fi) {                               // masked slice: constants
    int t = threadIdx.x;
    if (t < BPB) {
      int b = b0 + t;
      outVal[b * EDIM + e] = 1.0f;
      outOt [b * EDIM + e] = 0.0f;
    }
    return;
  }

  __shared__ __align__(16) __bf16 sB[64 * PDIM * 8];  // [oct][p][8] = 32 KiB
  __shared__ float sPNp[8][PDIM];                     // proto-norm partials
  __shared__ __align__(16) float sCw[4][16][36];      // wave-private cost tiles

  const int t  = threadIdx.x;
  const int l  = t & 63;
  const int w  = t >> 6;              // wave 0..3 -> problems b0+8w .. +7
  const int fr = l & 15;              // fragment lane index (M-row / N-col)
  const int q4 = l >> 4;              // k-slice selector (0..3)

  // ---- A-fragment pointer: M-rows 0-7 tokens, 8-15 anchors ------------------
  const int bRow = b0 + 8 * w + (fr & 7);
  const int eSel = (fr < 8) ? e : fi;
  const float4* rp4 = (const float4*)(tokens + ((size_t)bRow * EDIM + eSel) * DDIM);

  // chunk-0 A prefetch (in flight during proto staging)
  float4 ca0 = rp4[q4 * 2];
  float4 ca1 = rp4[q4 * 2 + 1];

  // ---- stage protos[e] -> bf16 LDS + fp32 norm partials ---------------------
  {
    const float4* pG4 = (const float4*)(protos + (size_t)e * PDIM * DDIM);
    const int p  = t & 31;
    const int oh = t >> 5;            // 0..7
    float pnp = 0.f;
    #pragma unroll
    for (int pass = 0; pass < 8; ++pass) {
      int oct = oh * 8 + pass;        // k = [oct*8, oct*8+8)
      float4 a = pG4[p * 128 + oct * 2];
      float4 b = pG4[p * 128 + oct * 2 + 1];
      pnp += a.x*a.x + a.y*a.y + a.z*a.z + a.w*a.w
           + b.x*b.x + b.y*b.y + b.z*b.z + b.w*b.w;
      *(bf16x8*)&sB[(oct * PDIM + p) * 8] = cvt2(a, b);
    }
    sPNp[oh][p] = pnp;
  }
  __syncthreads();                    // the ONLY barrier

  // ---- K-loop: direct-global A fragments, LDS B fragments, 2 MFMA/chunk -----
  f32x4 acc0 = (f32x4){0.f, 0.f, 0.f, 0.f};
  f32x4 acc1 = (f32x4){0.f, 0.f, 0.f, 0.f};
  float ss = 0.f;                     // partial ||row fr||^2 over this lane's k

  #pragma unroll
  for (int kc = 0; kc < 16; ++kc) {
    float4 na0, na1;
    if (kc < 15) {                    // next chunk's A (no barrier in the way)
      na0 = rp4[(kc + 1) * 8 + q4 * 2];
      na1 = rp4[(kc + 1) * 8 + q4 * 2 + 1];
    }
    ss += ca0.x*ca0.x + ca0.y*ca0.y + ca0.z*ca0.z + ca0.w*ca0.w
        + ca1.x*ca1.x + ca1.y*ca1.y + ca1.z*ca1.z + ca1.w*ca1.w;
    bf16x8 aF  = cvt2(ca0, ca1);
    bf16x8 bF0 = *(const bf16x8*)&sB[((kc * 4 + q4) * PDIM + fr) * 8];
    bf16x8 bF1 = *(const bf16x8*)&sB[((kc * 4 + q4) * PDIM + 16 + fr) * 8];
    acc0 = __builtin_amdgcn_mfma_f32_16x16x32_bf16(aF, bF0, acc0, 0, 0, 0);
    acc1 = __builtin_amdgcn_mfma_f32_16x16x32_bf16(aF, bF1, acc1, 0, 0, 0);
    ca0 = na0; ca1 = na1;
  }

  // ---- norms: full row norm in every lane, then per-C/D-row via bpermute ----
  ss += __shfl_xor(ss, 16);
  ss += __shfl_xor(ss, 32);           // lanes (fr,*) now hold ||row fr||^2
  float pn_a = 0.f, pn_b = 0.f;       // proto norms for cols fr, 16+fr
  #pragma unroll
  for (int o = 0; o < 8; ++o) {
    pn_a += sPNp[o][fr];
    pn_b += sPNp[o][16 + fr];
  }

  // ---- epilogue: cost -> wave-private LDS tile ------------------------------
  #pragma unroll
  for (int reg = 0; reg < 4; ++reg) {
    int row = q4 * 4 + reg;           // C/D: row=(l>>4)*4+reg, col=fr
    float nrm = __shfl(ss, row);      // norm of M-row `row`
    sCw[w][row][fr]      = fmaxf(nrm - 2.f * acc0[reg] + pn_a, 0.f);
    sCw[w][row][16 + fr] = fmaxf(nrm - 2.f * acc1[reg] + pn_b, 0.f);
  }
  // DS pipe is in-order per wave: reads below see the writes above.

  // ---- Sinkhorn: 8 lanes/problem, 4 p each ----------------------------------
  const int i = l & 7;                // problem 0..7 within wave
  const int s = l >> 3;               // p-slice: p in [4s, 4s+4)
  float c0[4], c1[4];
  {
    float4 v0 = *(const float4*)&sCw[w][i][4 * s];       // token costs
    float4 v1 = *(const float4*)&sCw[w][8 + i][4 * s];   // anchor costs
    c0[0] = v0.x; c0[1] = v0.y; c0[2] = v0.z; c0[3] = v0.w;
    c1[0] = v1.x; c1[1] = v1.y; c1[2] = v1.z; c1[3] = v1.w;
  }

  float W[4], dc[4];
  float sum0 = 0.f, mA = -1e30f, mB = -1e30f;
  #pragma unroll
  for (int r = 0; r < 4; ++r) {
    float ka = -c0[r] * C_SCALE, kb = -c1[r] * C_SCALE;
    dc[r] = c1[r] - c0[r];
    sum0 += c0[r];
    mA = fmaxf(mA, ka);
    mB = fmaxf(mB, kb);
  }
  mA = fmaxf(mA, __shfl_xor(mA, 8));
  mA = fmaxf(mA, __shfl_xor(mA, 16));
  mA = fmaxf(mA, __shfl_xor(mA, 32));
  mB = fmaxf(mB, __shfl_xor(mB, 8));
  mB = fmaxf(mB, __shfl_xor(mB, 16));
  mB = fmaxf(mB, __shfl_xor(mB, 32));
  float sa = 0.f, sb = 0.f;
  #pragma unroll
  for (int r = 0; r < 4; ++r) {
    float ka = -c0[r] * C_SCALE, kb = -c1[r] * C_SCALE;
    sa += EXP2F(ka - mA);
    sb += EXP2F(kb - mB);
    W[r] = EXP2F(C_SCALE * dc[r]);    // 2^(k0-k1)
  }
  sa += __shfl_xor(sa, 8);  sa += __shfl_xor(sa, 16);  sa += __shfl_xor(sa, 32);
  sb += __shfl_xor(sb, 8);  sb += __shfl_xor(sb, 16);  sb += __shfl_xor(sb, 32);
  sum0 += __shfl_xor(sum0, 8);
  sum0 += __shfl_xor(sum0, 16);
  sum0 += __shfl_xor(sum0, 32);
  // iteration 1 (reference: lv=0): delta1 = lse2(k1) - lse2(k0)
  float delta = (mB + LOG2F(sb)) - (mA + LOG2F(sa));

  // iterations 2..50 with fp32-noise early exit (bit-equivalent to full run)
  for (int it = 0; it < 49; ++it) {
    float s2 = EXP2F(delta);
    float T = 0.f;
    #pragma unroll
    for (int r = 0; r < 4; ++r)
      T += RCPF(__builtin_fmaf(W[r], s2, 1.0f));   // sigma_p
    T += __shfl_xor(T, 8);
    T += __shfl_xor(T, 16);
    T += __shfl_xor(T, 32);           // in (0,32)
    float upd = LOG2F(T) - LOG2F(32.0f - T);
    delta += upd;
    if (__ballot(fabsf(upd) > 5e-7f) == 0ull) break;
  }

  // ---- final transport & outputs -------------------------------------------
  float s2 = EXP2F(delta), sv = 0.f;
  #pragma unroll
  for (int r = 0; r < 4; ++r)
    sv += RCPF(__builtin_fmaf(W[r], s2, 1.0f)) * dc[r];
  sv += __shfl_xor(sv, 8);
  sv += __shfl_xor(sv, 16);
  sv += __shfl_xor(sv, 32);
  if (s == 0) {
    int b = b0 + 8 * w + i;
    float ot  = (sum0 + sv) * 0.03125f;
    float val = RCPF(1.0f + EXP2F(LOG2E * 6.0f * (ot - 0.25f)));
    outVal[b * EDIM + e] = val;
    outOt [b * EDIM + e] = ot;
  }
}

extern "C" void kernel_launch(void* const* d_in, const int* in_sizes, int n_in,
                              void* d_out, int out_size, void* d_ws, size_t ws_size,
                              hipStream_t stream) {
  const float* tokens = (const float*)d_in[0];   // (8192, 8, 512) fp32
  const float* protos = (const float*)d_in[1];   // (8, 32, 512) fp32
  const int*   fidx   = (const int*)d_in[2];     // scalar
  float* out = (float*)d_out;                    // 65536 validity + 65536 ot

  dim3 grid((BDIM / BPB) * EDIM);                // 2048 blocks, chunk-major
  ot_noise_gate_kernel<<<grid, NTHR, 0, stream>>>(tokens, protos, fidx, out);
}

// Round 6
// 206.365 us; speedup vs baseline: 1.0589x; 1.0094x over previous
//
#include <hip/hip_runtime.h>
#include <hip/hip_bf16.h>

// OTNoiseGate: B=8192, E=8, D=512, P=32, eps=0.05, 50 Sinkhorn iters.
// R6 = R5 (barrier-free waves, direct-global A fragments, LDS B tile,
// ns=2 scalar-recurrence Sinkhorn w/ early exit) + 4-deep register prefetch
// on A (the R5 post-mortem showed the K-loop was MLP-starved: 2KB/wave in
// flight vs the ~9.2KB/CU Little's-law requirement -> HBM ran at ~1.8TB/s).

#define EXP2F(x) __builtin_amdgcn_exp2f(x)
#define LOG2F(x) __builtin_amdgcn_logf(x)   // v_log_f32 = log2
#define RCPF(x)  __builtin_amdgcn_rcpf(x)

typedef __bf16 bf16x8 __attribute__((ext_vector_type(8)));
typedef float  f32x4  __attribute__((ext_vector_type(4)));

#define BDIM 8192
#define EDIM 8
#define DDIM 512
#define PDIM 32
#define BPB  32             // problems per block (8 per wave x 4 waves)
#define NTHR 256
#define PFD  4              // prefetch depth (chunks in flight per lane)
#define C_SCALE 28.853900817779268f   // log2(e)/eps
#define LOG2E   1.4426950408889634f

__device__ __forceinline__ bf16x8 cvt2(float4 a, float4 b) {
  bf16x8 r;
  r[0] = (__bf16)a.x; r[1] = (__bf16)a.y; r[2] = (__bf16)a.z; r[3] = (__bf16)a.w;
  r[4] = (__bf16)b.x; r[5] = (__bf16)b.y; r[6] = (__bf16)b.z; r[7] = (__bf16)b.w;
  return r;
}

__global__ __launch_bounds__(NTHR, 3)    // 3 blocks/CU, VGPR cap 170
void ot_noise_gate_kernel(const float* __restrict__ tokens,
                          const float* __restrict__ protos,
                          const int*   __restrict__ fullIndexPtr,
                          float*       __restrict__ out) {
  const int fi    = fullIndexPtr[0];
  const int e     = blockIdx.x & (EDIM - 1);   // chunk-major: anchor L3 reuse
  const int b0    = (blockIdx.x >> 3) * BPB;
  float* outVal = out;                         // validity (B,E,1)
  float* outOt  = out + BDIM * EDIM;           // ot_cost  (B,E)

  if (e == fi) {                               // masked slice: constants
    int t = threadIdx.x;
    if (t < BPB) {
      int b = b0 + t;
      outVal[b * EDIM + e] = 1.0f;
      outOt [b * EDIM + e] = 0.0f;
    }
    return;
  }

  __shared__ __align__(16) __bf16 sB[64 * PDIM * 8];  // [oct][p][8] = 32 KiB
  __shared__ float sPNp[8][PDIM];                     // proto-norm partials
  __shared__ __align__(16) float sCw[4][16][36];      // wave-private cost tiles

  const int t  = threadIdx.x;
  const int l  = t & 63;
  const int w  = t >> 6;              // wave 0..3 -> problems b0+8w .. +7
  const int fr = l & 15;              // fragment lane index (M-row / N-col)
  const int q4 = l >> 4;              // k-slice selector (0..3)

  // ---- A-fragment pointer: M-rows 0-7 tokens, 8-15 anchors ------------------
  const int bRow = b0 + 8 * w + (fr & 7);
  const int eSel = (fr < 8) ? e : fi;
  const float4* rp4 = (const float4*)(tokens + ((size_t)bRow * EDIM + eSel) * DDIM);

  // prefetch chunks 0..PFD-1 (in flight during proto staging + barrier drain)
  float4 buf[PFD][2];
  #pragma unroll
  for (int c = 0; c < PFD; ++c) {
    buf[c][0] = rp4[c * 8 + q4 * 2];
    buf[c][1] = rp4[c * 8 + q4 * 2 + 1];
  }

  // ---- stage protos[e] -> bf16 LDS + fp32 norm partials ---------------------
  {
    const float4* pG4 = (const float4*)(protos + (size_t)e * PDIM * DDIM);
    const int p  = t & 31;
    const int oh = t >> 5;            // 0..7
    float pnp = 0.f;
    #pragma unroll
    for (int pass = 0; pass < 8; ++pass) {
      int oct = oh * 8 + pass;        // k = [oct*8, oct*8+8)
      float4 a = pG4[p * 128 + oct * 2];
      float4 b = pG4[p * 128 + oct * 2 + 1];
      pnp += a.x*a.x + a.y*a.y + a.z*a.z + a.w*a.w
           + b.x*b.x + b.y*b.y + b.z*b.z + b.w*b.w;
      *(bf16x8*)&sB[(oct * PDIM + p) * 8] = cvt2(a, b);
    }
    sPNp[oh][p] = pnp;
  }
  __syncthreads();                    // the ONLY barrier

  // ---- K-loop: 4-deep pipelined global A, LDS B, 2 MFMA/chunk ---------------
  f32x4 acc0 = (f32x4){0.f, 0.f, 0.f, 0.f};
  f32x4 acc1 = (f32x4){0.f, 0.f, 0.f, 0.f};
  float ss = 0.f;                     // partial ||row fr||^2 over this lane's k

  #pragma unroll
  for (int kc = 0; kc < 16; ++kc) {
    float4 ca0 = buf[kc % PFD][0];
    float4 ca1 = buf[kc % PFD][1];
    if (kc < 16 - PFD) {              // refill slot; lands PFD chunks ahead
      buf[kc % PFD][0] = rp4[(kc + PFD) * 8 + q4 * 2];
      buf[kc % PFD][1] = rp4[(kc + PFD) * 8 + q4 * 2 + 1];
    }
    ss += ca0.x*ca0.x + ca0.y*ca0.y + ca0.z*ca0.z + ca0.w*ca0.w
        + ca1.x*ca1.x + ca1.y*ca1.y + ca1.z*ca1.z + ca1.w*ca1.w;
    bf16x8 aF  = cvt2(ca0, ca1);
    bf16x8 bF0 = *(const bf16x8*)&sB[((kc * 4 + q4) * PDIM + fr) * 8];
    bf16x8 bF1 = *(const bf16x8*)&sB[((kc * 4 + q4) * PDIM + 16 + fr) * 8];
    acc0 = __builtin_amdgcn_mfma_f32_16x16x32_bf16(aF, bF0, acc0, 0, 0, 0);
    acc1 = __builtin_amdgcn_mfma_f32_16x16x32_bf16(aF, bF1, acc1, 0, 0, 0);
  }

  // ---- norms: reduce the 4 k-slices of each row -----------------------------
  ss += __shfl_xor(ss, 16);
  ss += __shfl_xor(ss, 32);           // lanes (fr,*) now hold ||row fr||^2
  float pn_a = 0.f, pn_b = 0.f;       // proto norms for cols fr, 16+fr
  #pragma unroll
  for (int o = 0; o < 8; ++o) {
    pn_a += sPNp[o][fr];
    pn_b += sPNp[o][16 + fr];
  }

  // ---- epilogue: cost -> wave-private LDS tile ------------------------------
  #pragma unroll
  for (int reg = 0; reg < 4; ++reg) {
    int row = q4 * 4 + reg;           // C/D: row=(l>>4)*4+reg, col=fr
    float nrm = __shfl(ss, row);      // norm of M-row `row`
    sCw[w][row][fr]      = fmaxf(nrm - 2.f * acc0[reg] + pn_a, 0.f);
    sCw[w][row][16 + fr] = fmaxf(nrm - 2.f * acc1[reg] + pn_b, 0.f);
  }
  // DS pipe is in-order per wave: reads below see the writes above.

  // ---- Sinkhorn: 8 lanes/problem, 4 p each ----------------------------------
  const int i = l & 7;                // problem 0..7 within wave
  const int s = l >> 3;               // p-slice: p in [4s, 4s+4)
  float c0[4], c1[4];
  {
    float4 v0 = *(const float4*)&sCw[w][i][4 * s];       // token costs
    float4 v1 = *(const float4*)&sCw[w][8 + i][4 * s];   // anchor costs
    c0[0] = v0.x; c0[1] = v0.y; c0[2] = v0.z; c0[3] = v0.w;
    c1[0] = v1.x; c1[1] = v1.y; c1[2] = v1.z; c1[3] = v1.w;
  }

  float W[4], dc[4];
  float sum0 = 0.f, mA = -1e30f, mB = -1e30f;
  #pragma unroll
  for (int r = 0; r < 4; ++r) {
    float ka = -c0[r] * C_SCALE, kb = -c1[r] * C_SCALE;
    dc[r] = c1[r] - c0[r];
    sum0 += c0[r];
    mA = fmaxf(mA, ka);
    mB = fmaxf(mB, kb);
  }
  mA = fmaxf(mA, __shfl_xor(mA, 8));
  mA = fmaxf(mA, __shfl_xor(mA, 16));
  mA = fmaxf(mA, __shfl_xor(mA, 32));
  mB = fmaxf(mB, __shfl_xor(mB, 8));
  mB = fmaxf(mB, __shfl_xor(mB, 16));
  mB = fmaxf(mB, __shfl_xor(mB, 32));
  float sa = 0.f, sb = 0.f;
  #pragma unroll
  for (int r = 0; r < 4; ++r) {
    float ka = -c0[r] * C_SCALE, kb = -c1[r] * C_SCALE;
    sa += EXP2F(ka - mA);
    sb += EXP2F(kb - mB);
    W[r] = EXP2F(C_SCALE * dc[r]);    // 2^(k0-k1)
  }
  sa += __shfl_xor(sa, 8);  sa += __shfl_xor(sa, 16);  sa += __shfl_xor(sa, 32);
  sb += __shfl_xor(sb, 8);  sb += __shfl_xor(sb, 16);  sb += __shfl_xor(sb, 32);
  sum0 += __shfl_xor(sum0, 8);
  sum0 += __shfl_xor(sum0, 16);
  sum0 += __shfl_xor(sum0, 32);
  // iteration 1 (reference: lv=0): delta1 = lse2(k1) - lse2(k0)
  float delta = (mB + LOG2F(sb)) - (mA + LOG2F(sa));

  // iterations 2..50 with fp32-noise early exit (bit-equivalent to full run)
  for (int it = 0; it < 49; ++it) {
    float s2 = EXP2F(delta);
    float T = 0.f;
    #pragma unroll
    for (int r = 0; r < 4; ++r)
      T += RCPF(__builtin_fmaf(W[r], s2, 1.0f));   // sigma_p
    T += __shfl_xor(T, 8);
    T += __shfl_xor(T, 16);
    T += __shfl_xor(T, 32);           // in (0,32)
    float upd = LOG2F(T) - LOG2F(32.0f - T);
    delta += upd;
    if (__ballot(fabsf(upd) > 5e-7f) == 0ull) break;
  }

  // ---- final transport & outputs -------------------------------------------
  float s2 = EXP2F(delta), sv = 0.f;
  #pragma unroll
  for (int r = 0; r < 4; ++r)
    sv += RCPF(__builtin_fmaf(W[r], s2, 1.0f)) * dc[r];
  sv += __shfl_xor(sv, 8);
  sv += __shfl_xor(sv, 16);
  sv += __shfl_xor(sv, 32);
  if (s == 0) {
    int b = b0 + 8 * w + i;
    float ot  = (sum0 + sv) * 0.03125f;
    float val = RCPF(1.0f + EXP2F(LOG2E * 6.0f * (ot - 0.25f)));
    outVal[b * EDIM + e] = val;
    outOt [b * EDIM + e] = ot;
  }
}

extern "C" void kernel_launch(void* const* d_in, const int* in_sizes, int n_in,
                              void* d_out, int out_size, void* d_ws, size_t ws_size,
                              hipStream_t stream) {
  const float* tokens = (const float*)d_in[0];   // (8192, 8, 512) fp32
  const float* protos = (const float*)d_in[1];   // (8, 32, 512) fp32
  const int*   fidx   = (const int*)d_in[2];     // scalar
  float* out = (float*)d_out;                    // 65536 validity + 65536 ot

  dim3 grid((BDIM / BPB) * EDIM);                // 2048 blocks, chunk-major
  ot_noise_gate_kernel<<<grid, NTHR, 0, stream>>>(tokens, protos, fidx, out);
}